// Round 5
// baseline (61570.898 us; speedup 1.0000x reference)
//
#include <hip/hip_runtime.h>

#define H    50
#define T    65536
#define NTHREADS 512

// ws layout (floats)
#define WC1_OFF 0        // 200*64
#define WC2_OFF 12800    // 200*128

// Prep: permute rows (orig r = gate*50+j -> new r' = j*4+gate), pad cols,
// and fold biases into a constant-1 input column:
// Wc1: 200 x 64  : 0..6 = W_ih1[:,0:7], 7 = W_ih1[:,7] (err weight; its input
//                  col is ALWAYS 0 in the matvec — err handled in regs),
//                  8..57 = W_hh1, 58 = b_ih1+b_hh1 (input col 58 == 1.0),
//                  59..63 = 0
// Wc2: 200 x 128 : 0..49 = W_ih2, 50..99 = W_hh2, 100 = b_ih2+b_hh2 (input
//                  col 100 == 1.0), 101..127 = 0
__global__ void prep_kernel(const float* __restrict__ Wih1, const float* __restrict__ Whh1,
                            const float* __restrict__ bih1, const float* __restrict__ bhh1,
                            const float* __restrict__ Wih2, const float* __restrict__ Whh2,
                            const float* __restrict__ bih2, const float* __restrict__ bhh2,
                            float* __restrict__ ws) {
  int idx = blockIdx.x * blockDim.x + threadIdx.x;
  if (idx < 200 * 64) {
    int nr = idx >> 6, c = idx & 63;
    int j = nr >> 2, gate = nr & 3, r = gate * 50 + j;
    float v = 0.f;
    if (c < 8) v = Wih1[r * 8 + c];
    else if (c < 58) v = Whh1[r * 50 + (c - 8)];
    else if (c == 58) v = bih1[r] + bhh1[r];
    ws[WC1_OFF + idx] = v;
  }
  if (idx < 200 * 128) {
    int nr = idx >> 7, c = idx & 127;
    int j = nr >> 2, gate = nr & 3, r = gate * 50 + j;
    float v = 0.f;
    if (c < 50) v = Wih2[r * 50 + c];
    else if (c < 100) v = Whh2[r * 50 + (c - 50)];
    else if (c == 100) v = bih2[r] + bhh2[r];
    ws[WC2_OFF + idx] = v;
  }
}

__device__ __forceinline__ float sigm(float x) {
  return __builtin_amdgcn_rcpf(1.f + __expf(-x));
}
__device__ __forceinline__ float tanh_(float x) {
  return 1.f - 2.f * __builtin_amdgcn_rcpf(1.f + __expf(2.f * x));
}
__device__ __forceinline__ void bar() {
  asm volatile("s_waitcnt lgkmcnt(0)\n\ts_barrier" ::: "memory");
}
// 0xB1 = quad_perm xor1 ; 0x4E = quad_perm xor2 ; 0x141 = row_half_mirror
// (after xor1+xor2 value is quad-uniform; 0x141 completes an 8-lane reduce,
//  leaving the sum uniform across all 8 lanes) ; 0x140 = row_mirror (16-lane)
template<int CTRL>
__device__ __forceinline__ float dpp_add(float x) {
  int y = __builtin_amdgcn_mov_dpp(__float_as_int(x), CTRL, 0xF, 0xF, true);
  return x + __int_as_float(y);
}

// logical column -> chunk-padded LDS word: 16-float chunks at stride 20.
// Per-instruction addresses across the 8 slices: 20p%32 = {0,20,8,28,16,4,24,12}
// — all 8 bank-quads disjoint -> conflict-free column-sliced reads.
__device__ __forceinline__ int phys(int c) { return (c >> 4) * 20 + (c & 15); }

// ============================================================================
// R4 post-mortem: VGPR=88 with waves_per_eu(2,2) applied (SGPR 48->112 proves
// it) and time unchanged -> spill theory dead (AGPR operands are free on the
// unified file). New theory: 164 broadcast ds_read_b128/step @ ~12cy LDS-pipe
// occupancy each ~ 1970cy ~ the whole 2237cy step. This kernel keeps the
// 2-phase schedule but switches both matvecs to COLUMN-SLICED form:
//   cell-2: 200 lanes (tid<200 of waves 0-3): group g=tid>>3 owns rows
//           8g..8g+7; slice p=tid&7 covers logical cols 16p..16p+15 (CIN,
//           chunk-padded). 4 ds_read_b128/lane, 128 FMA, 3-stage DPP reduce
//           -> sums uniform in group; lanes tid&3==0 (units u=tid>>2) do the
//           gate math, write h2 and WY.
//   cell-1 partial (t+1): 200 lanes (tid-256 in waves 4-7): same but 8-col
//           half-chunk slices of AIN. 2 reads/lane, 64 FMA, reduce; slice
//           lanes 0/1 write PART[4m..4m+3] as b128.
// LDS instrs/step: ~44 vs 164. Bias via constant-1 column; err via werr regs.
// PHASE2 (wave 0) identical to R4.
// ============================================================================

#define DOT(k,c,u) { a##k += W##k##_##c.x*(u).x; a##k += W##k##_##c.y*(u).y; \
                     a##k += W##k##_##c.z*(u).z; a##k += W##k##_##c.w*(u).w; }
#define ROW8(c,u) DOT(0,c,u) DOT(1,c,u) DOT(2,c,u) DOT(3,c,u) \
                  DOT(4,c,u) DOT(5,c,u) DOT(6,c,u) DOT(7,c,u)
#define RED8(k) { a##k = dpp_add<0xB1>(a##k); a##k = dpp_add<0x4E>(a##k); \
                  a##k = dpp_add<0x141>(a##k); }

#define CELL2(par) {                                                 \
    const float4* CU = (const float4*)CIN[par];                      \
    float a0=0.f,a1=0.f,a2=0.f,a3=0.f,a4=0.f,a5=0.f,a6=0.f,a7=0.f;   \
    float4 u4;                                                       \
    u4 = CU[cbase+0]; ROW8(0,u4)                                     \
    u4 = CU[cbase+1]; ROW8(1,u4)                                     \
    u4 = CU[cbase+2]; ROW8(2,u4)                                     \
    u4 = CU[cbase+3]; ROW8(3,u4)                                     \
    RED8(0) RED8(1) RED8(2) RED8(3) RED8(4) RED8(5) RED8(6) RED8(7)  \
    if (own2) {                                                      \
      float s0 = (tid&4)? a4:a0, s1 = (tid&4)? a5:a1;                \
      float s2 = (tid&4)? a6:a2, s3 = (tid&4)? a7:a3;                \
      float gi = sigm(s0), gf = sigm(s1), gg = tanh_(s2), go = sigm(s3); \
      c2 = gf*c2 + gi*gg;                                            \
      float h2v = go * tanh_(c2);                                    \
      CIN[(par)^1][h2off] = h2v;                                     \
      WY[uo] = wo * h2v;                                             \
    } }

#define HELPER(par) {                                                \
    const float4* AU = (const float4*)AIN[(par)^1];                  \
    float a0=0.f,a1=0.f,a2=0.f,a3=0.f,a4=0.f,a5=0.f,a6=0.f,a7=0.f;   \
    float4 ua = AU[abase+0], ub = AU[abase+1];                       \
    ROW8(0,ua) ROW8(1,ub)                                            \
    RED8(0) RED8(1) RED8(2) RED8(3) RED8(4) RED8(5) RED8(6) RED8(7)  \
    if (ph < 2) {                                                    \
      float4 pv;                                                     \
      pv.x = ph? a4:a0; pv.y = ph? a5:a1;                            \
      pv.z = ph? a6:a2; pv.w = ph? a7:a3;                            \
      *(float4*)&PART[4*pm] = pv;                                    \
    } }

#define PHASE2(t, par, doY) {                                        \
    if (tid < 64) {                                                  \
      float4 pq = *(const float4*)&PART[4 * tid];                    \
      if (doY) {                                                     \
        float v = WY[tid];                                           \
        float actd = ACT4[(t) & 3];                                  \
        v = dpp_add<0xB1>(v); v = dpp_add<0x4E>(v);                  \
        v = dpp_add<0x141>(v); v = dpp_add<0x140>(v);                \
        v = v + __int_as_float(__builtin_amdgcn_ds_swizzle(__float_as_int(v), 0x401F)); \
        float vlo = __int_as_float(__builtin_amdgcn_readlane(__float_as_int(v), 0));  \
        float vhi = __int_as_float(__builtin_amdgcn_readlane(__float_as_int(v), 32)); \
        float y = vlo + vhi + bo;                                    \
        if (tid == 0) out[t] = y;                                    \
        err = 0.9f * err + 0.1f * (actd - y);                        \
      }                                                              \
      float gi = sigm (pq.x + werr0 * err);                          \
      float gf = sigm (pq.y + werr1 * err);                          \
      float gg = tanh_(pq.z + werr2 * err);                          \
      float go = sigm (pq.w + werr3 * err);                          \
      c1 = gf * c1 + gi * gg;                                        \
      float h1 = go * tanh_(c1);                                     \
      if (tid < 50) {                                                \
        CIN[(par) ^ 1][h1cOff] = h1;                                 \
        AIN[par][h1aOff]       = h1;                                 \
      }                                                              \
    } else if (tid >= 504) {                                         \
      int c = tid - 504;                                             \
      if (c < 7) AIN[par][c] = xr; else ACT4[((t) + 2) & 3] = xr;    \
      int nt = ((t) + 3 < T) ? (t) + 3 : T - 1;                      \
      xr = xseq[nt * 8 + c];                                         \
    } }

__launch_bounds__(NTHREADS)
__attribute__((amdgpu_waves_per_eu(2, 2)))
__global__ void lstm_kernel(const float* __restrict__ xseq,
                            const float* __restrict__ ws,
                            const float* __restrict__ Wout,
                            const float* __restrict__ bout,
                            float* __restrict__ out) {
  // Chunk-padded (stride-20) state vectors; pads stay 0, "one" slots stay 1.
  // AIN logical 64 : [x(0..6) | err-slot 0 @7 | h1 @8..57 | 1.0 @58 | 0]
  // CIN logical 128: [h1(0..49) | h2 @50..99 | 1.0 @100 | 0]
  __shared__ __align__(16) float AIN[2][80];
  __shared__ __align__(16) float CIN[2][160];
  __shared__ __align__(16) float PART[256];   // dense rows; [200..256) stay 0
  __shared__ __align__(16) float WY[64];      // wo[u]*h2[u], 50..63 = 0
  __shared__ float ACT4[4];                   // act_dist ring, depth 4

  const int tid = threadIdx.x;
  const float* Wc1 = ws + WC1_OFF;
  const float* Wc2 = ws + WC2_OFF;

  for (int i = tid; i < 2 * 80;  i += NTHREADS) ((float*)AIN)[i] = 0.f;
  for (int i = tid; i < 2 * 160; i += NTHREADS) ((float*)CIN)[i] = 0.f;
  for (int i = tid; i < 256;     i += NTHREADS) PART[i] = 0.f;
  if (tid < 64) WY[tid] = 0.f;
  if (tid < 4)  ACT4[tid] = 0.f;

  // ---- per-lane role constants ----
  const int g     = tid >> 3;          // cell-2 row-group (rows 8g..8g+7)
  const int fp    = tid & 7;           // cell-2 col slice (16 cols)
  const int cbase = fp * 5;            // float4 index of chunk fp (stride 20)
  const bool own2 = (tid < 256) && ((tid & 3) == 0) && (g < 25);
  const int uo    = tid >> 2;          // owner's unit
  const int h2off = phys(50 + (uo & 63));
  const int hr    = tid - 256;         // helper index
  const int gh    = hr >> 3;           // cell-1 row-group
  const int ph    = hr & 7;            // cell-1 col slice (8 cols)
  const int abase = 5 * (ph >> 1) + 2 * (ph & 1);
  const int pm    = 2 * gh + (ph & 1); // PART quad index (writers ph<2)
  const int h1cOff = phys(tid & 63);        // PHASE2 h1 -> CIN col tid
  const int h1aOff = phys(8 + (tid & 63));  // PHASE2 h1 -> AIN col 8+tid

  // ---- weight registers: 32 named float4 (union across roles) ----
  const float4 z4 = make_float4(0.f, 0.f, 0.f, 0.f);
  float4 W0_0=z4,W0_1=z4,W0_2=z4,W0_3=z4, W1_0=z4,W1_1=z4,W1_2=z4,W1_3=z4,
         W2_0=z4,W2_1=z4,W2_2=z4,W2_3=z4, W3_0=z4,W3_1=z4,W3_2=z4,W3_3=z4,
         W4_0=z4,W4_1=z4,W4_2=z4,W4_3=z4, W5_0=z4,W5_1=z4,W5_2=z4,W5_3=z4,
         W6_0=z4,W6_1=z4,W6_2=z4,W6_3=z4, W7_0=z4,W7_1=z4,W7_2=z4,W7_3=z4;
  float c1 = 0.f, c2 = 0.f, err = 0.f, xr = 0.f;
  float wo = 0.f, bo = 0.f;
  float werr0 = 0.f, werr1 = 0.f, werr2 = 0.f, werr3 = 0.f;

#define LW2(k) { const float4* s = (const float4*)&Wc2[(8*g + k)*128 + 16*fp]; \
                 W##k##_0 = s[0]; W##k##_1 = s[1]; W##k##_2 = s[2]; W##k##_3 = s[3]; }
#define LW1(k) { const float4* s = (const float4*)&Wc1[(8*gh + k)*64 + 8*ph]; \
                 W##k##_0 = s[0]; W##k##_1 = s[1]; }

  if (tid < 256) {                     // cell-2 lanes (g<25 active)
    if (g < 25) { LW2(0) LW2(1) LW2(2) LW2(3) LW2(4) LW2(5) LW2(6) LW2(7) }
    if (own2) wo = Wout[uo];           // uo < 50 for owners
    if (tid < 64) {                    // wave 0: PHASE2 worker extras
      bo = bout[0];
      if (tid < 50) {
        werr0 = Wc1[(4 * tid + 0) * 64 + 7];
        werr1 = Wc1[(4 * tid + 1) * 64 + 7];
        werr2 = Wc1[(4 * tid + 2) * 64 + 7];
        werr3 = Wc1[(4 * tid + 3) * 64 + 7];
      }
    }
  } else if (tid < 456) {              // cell-1 helper lanes (gh 0..24)
    LW1(0) LW1(1) LW1(2) LW1(3) LW1(4) LW1(5) LW1(6) LW1(7)
  }
  __syncthreads();
  // constant-1 bias columns + x(0) preload (after zeroing; disjoint writers)
  if (tid == 0) {
    AIN[0][70] = 1.f; AIN[1][70] = 1.f;     // phys(58) = 70
    CIN[0][124] = 1.f; CIN[1][124] = 1.f;   // phys(100) = 124
  }
  if (tid >= 504) {
    int c = tid - 504;
    float v0 = xseq[c];
    if (c < 7) AIN[0][c] = v0; else ACT4[0] = v0;   // phys(c)=c for c<7
    xr = xseq[8 + c];
  }
  __syncthreads();

  // ---- prologue: pseudo-iteration t = -1 (par = 1), no y/err yet ----
  if (tid >= 256 && tid < 456) HELPER(1)   // PART(0) from AIN[0]=[x(0);h1=0;1]
  bar();
  PHASE2(-1, 1, false)                     // h1(0)->CIN[0],AIN[1]; x(1)->AIN[1]
  bar();

  #pragma unroll 1
  for (int t = 0; t < T; t += 2) {
    if (tid < 256) CELL2(0) else if (tid < 456) HELPER(0)
    bar();
    PHASE2(t, 0, true)
    bar();
    if (tid < 256) CELL2(1) else if (tid < 456) HELPER(1)
    bar();
    PHASE2(t + 1, 1, true)
    bar();
  }
}

extern "C" void kernel_launch(void* const* d_in, const int* in_sizes, int n_in,
                              void* d_out, int out_size, void* d_ws, size_t ws_size,
                              hipStream_t stream) {
  const float* xseq = (const float*)d_in[0];
  const float* Wih1 = (const float*)d_in[1];
  const float* Whh1 = (const float*)d_in[2];
  const float* bih1 = (const float*)d_in[3];
  const float* bhh1 = (const float*)d_in[4];
  const float* Wih2 = (const float*)d_in[5];
  const float* Whh2 = (const float*)d_in[6];
  const float* bih2 = (const float*)d_in[7];
  const float* bhh2 = (const float*)d_in[8];
  const float* Wout = (const float*)d_in[9];
  const float* bout = (const float*)d_in[10];
  float* ws = (float*)d_ws;

  prep_kernel<<<100, 256, 0, stream>>>(Wih1, Whh1, bih1, bhh1,
                                       Wih2, Whh2, bih2, bhh2, ws);
  lstm_kernel<<<1, NTHREADS, 0, stream>>>(xseq, ws, Wout, bout, (float*)d_out);
}